// Round 19
// baseline (802.452 us; speedup 1.0000x reference)
//
#include <hip/hip_runtime.h>
#include <math.h>

// -----------------------------------------------------------------------------
// Round 19 = r17 (best total: 126us; sample ~106us unprofiled) + ONE delta:
// traj folded into sample_kernel as a dedicated 5th wave per block.
// Ledger across r11/r16/r17/r18 shows traj+launch ~= 20us of every total.
// The 64-step f64 chain (~16us) is pure ALU on an otherwise ~80%-idle VALU;
// waves 0-3 stage tiles (memory-bound ~25us/generation) while wave 4 runs the
// chain; the single existing __syncthreads joins them (all traj consumers are
// post-barrier). Everything else byte-identical to r17: ballot x-compress,
// linear LDS u-stage, rotated scan, 2 exact cr_g, in-wave fixup, NT stores.
// d_ws: unused.
// -----------------------------------------------------------------------------

typedef float f4nt __attribute__((ext_vector_type(4)));

__device__ __forceinline__ float cr_logf32(float x) { return (float)log((double)x); }

__device__ __forceinline__ float cr_g(float u) {
    float c0 = __fadd_rn(u, 1e-30f);
    float t2 = cr_logf32(c0);
    float t3 = __fadd_rn(-t2, 1e-30f);
    float t4 = cr_logf32(t3);
    return -t4;
}

// branchless scan step: mask hot bin, track top-2 value + first-visited index
#define SCANB(VAL, IDX)                                         \
    {                                                           \
        const float cu = ((IDX) == hc) ? -1.0f : (VAL);         \
        const bool gt1 = cu > t1u;                              \
        const bool gt2 = cu > t2u;                              \
        t2u = gt1 ? t1u : (gt2 ? cu : t2u);                     \
        t1i = gt1 ? (IDX) : t1i;                                \
        t1u = gt1 ? cu : t1u;                                   \
    }

__global__ void __launch_bounds__(320) sample_kernel(
        const float4* __restrict__ log_x0,
        const float4* __restrict__ u,
        const float*  __restrict__ x0flat,
        const int*    __restrict__ t_ptr,
        float4* __restrict__ out) {
    __shared__ float lds_u[4][2048];             // 64 feat x 32 f32, per tile-wave
    __shared__ unsigned char lds_h[4][64];       // hot bin per feature
    __shared__ float lh_s[32], lc_s[32];
    __shared__ float coldv_s;
    __shared__ float ac_s[1001];                 // f32 alphas_cumprod
    __shared__ float init_s[2];                  // hotf, coldf

    const int w    = threadIdx.x >> 6;           // wave in block (0..4)
    const int lane = threadIdx.x & 63;
    const int tile = blockIdx.x * 4 + w;         // valid for w<4
    const size_t fb4 = (size_t)tile * 512;       // float4 base of tile

    if (w < 4) {
        // ---- tile waves: stage (r17 byte-identical) ----
        float4 xr[8];
        #pragma unroll
        for (int k = 0; k < 8; ++k) xr[k] = log_x0[fb4 + k * 64 + lane];
        float4 ur[8];
        #pragma unroll
        for (int k = 0; k < 8; ++k) ur[k] = u[fb4 + k * 64 + lane];

        const int sgb = lane & ~7;               // subgroup base lane
        #pragma unroll
        for (int k = 0; k < 8; ++k) {
            const float4 xv = xr[k];
            int p = -1;
            p = (xv.x > -1.0f) ? 0 : p;
            p = (xv.y > -1.0f) ? 1 : p;
            p = (xv.z > -1.0f) ? 2 : p;
            p = (xv.w > -1.0f) ? 3 : p;
            const unsigned long long bal = __ballot(p >= 0);
            const unsigned mm = (unsigned)((bal >> sgb) & 0xFFull);
            const int hlane = (int)__ffs(mm) - 1;        // 0..7 or -1
            const int psrc  = __shfl(p, sgb + ((hlane < 0) ? 0 : hlane), 64);
            const int hbin  = (hlane < 0) ? 255 : (hlane * 4 + psrc);
            if ((lane & 7) == 0)
                lds_h[w][k * 8 + (lane >> 3)] = (unsigned char)hbin;
        }
        #pragma unroll
        for (int k = 0; k < 8; ++k)
            *(float4*)&lds_u[w][k * 256 + lane * 4] = ur[k];
    } else {
        // ---- wave 4: trajectory (r16/r17 traj_kernel numerics, in-block) ----
        int t = *t_ptr;
        if (t > 1000) t = 1000;
        if (t < 0) t = 0;

        for (int s = lane; s <= t; s += 64) {    // faithful-f32 cosine schedule
            float a = __fdiv_rn((float)s, 1000.0f);
            float b = __fadd_rn(a, 0.008f);
            float c = __fdiv_rn(b, 1.008f);
            float d = __fmul_rn(c, 0x1.921fb6p+1f);  // fl32(pi)
            float e = __fmul_rn(d, 0.5f);
            float cs = (float)cos((double)e);        // CR f32 cos
            ac_s[s] = __fmul_rn(cs, cs);
        }
        if (lane == 0) {
            float hotf = -1e30f, coldf = 1e30f;
            for (int j = 0; j < 32; ++j) {
                float v = x0flat[j];
                hotf = fmaxf(hotf, v);
                coldf = fminf(coldf, v);
            }
            init_s[0] = hotf;
            init_s[1] = coldf;
            coldv_s   = coldf;
        }
        // within-wave LDS visibility: program order (compiler emits lgkmcnt)
        if (lane < 32) {
            const int h = lane;                  // hot-bin position (sum order)
            float lh = init_s[0];
            float lc = init_s[1];
            for (int k = 0; k < t; ++k) {
                float sg = __fsub_rn(1.0f, __fdiv_rn(ac_s[k + 1], ac_s[k]));
                float ph = (float)exp((double)lh);
                float pc = (float)exp((double)lc);
                float th = __fmul_rn(ph, 0.03125f);
                float tc = __fmul_rn(pc, 0.03125f);
                float acc = 0.0f;
                for (int i = 0; i < 32; ++i)
                    acc = __fadd_rn(acc, (i == h) ? th : tc);
                float s1  = __fsub_rn(1.0f, sg);
                float sm  = __fmul_rn(sg, acc);
                float phn = __fadd_rn(__fmul_rn(s1, ph), sm);
                float pcn = __fadd_rn(__fmul_rn(s1, pc), sm);
                lh = cr_logf32(__fadd_rn(phn, 1e-8f));
                lc = cr_logf32(__fadd_rn(pcn, 1e-8f));
            }
            lh_s[h] = lh;
            lc_s[h] = lc;
        }
    }

    __syncthreads();                             // joins traj + staged tiles

    if (w >= 4) return;

    // ---- per-lane: own one feature; rotated float4 reads (r17) ----
    const int   h  = (int)lds_h[w][lane];
    const int   hc = (h > 31) ? 0 : h;
    const float lh = lh_s[hc];
    const float lc = lc_s[hc];
    const float coldv = coldv_s;
    const float4* urow4 = (const float4*)&lds_u[w][lane * 32];

    float t1u = -1.0f, t2u = -1.0f; int t1i = 0;
    #pragma unroll
    for (int q = 0; q < 8; ++q) {
        const int qq = (q + lane) & 7;           // bank rotation across lanes
        const float4 v = urow4[qq];
        const int b0 = qq * 4;
        SCANB(v.x, b0) SCANB(v.y, b0 + 1) SCANB(v.z, b0 + 2) SCANB(v.w, b0 + 3)
    }
    const float uhot = lds_u[w][lane * 32 + hc];

    const float s_hot  = __fadd_rn(lh, cr_g(uhot));
    const float s_cold = __fadd_rn(lc, cr_g(t1u));
    int widx;
    if (s_hot > s_cold)      widx = hc;
    else if (s_hot < s_cold) widx = t1i;
    else                     widx = (hc < t1i) ? hc : t1i;   // exact tie

    // ---- in-wave exact fixup for plateau/defensive features (r17) ----
    const bool flagged = ((t1u - t2u) < 1e-6f) | (h > 31);
    unsigned long long fm = __ballot(flagged);
    while (fm) {                                 // wave-uniform loop, rare
        const int fl = (int)__builtin_ctzll(fm);
        fm &= fm - 1;
        const int fh  = (int)lds_h[w][fl];
        const int fhc = (fh > 31) ? 0 : fh;
        const int l32 = lane & 31;
        const float uj  = lds_u[w][fl * 32 + l32];
        const bool jhot = (l32 == fhc) && (fh <= 31);
        float s = __fadd_rn(jhot ? lh_s[fhc] : lc_s[fhc], cr_g(uj));
        int idx = l32;
        #pragma unroll
        for (int m = 16; m > 0; m >>= 1) {
            float os = __shfl_xor(s,   m, 32);
            int   oi = __shfl_xor(idx, m, 32);
            if (os > s || (os == s && oi < idx)) { s = os; idx = oi; }
        }
        if (lane == fl) widx = idx;              // owner lane takes exact result
    }

    // ---- store: coalesced all-cold, winner patched via shfl; NT stores ----
    #pragma unroll
    for (int k = 0; k < 8; ++k) {
        const int src = k * 8 + (lane >> 3);     // owner lane of this float4
        const int wk  = __shfl(widx, src, 64);
        const int qb  = (lane & 7) * 4;          // bins covered: qb..qb+3
        f4nt o;
        o.x = (wk == qb    ) ? 0.0f : coldv;
        o.y = (wk == qb + 1) ? 0.0f : coldv;
        o.z = (wk == qb + 2) ? 0.0f : coldv;
        o.w = (wk == qb + 3) ? 0.0f : coldv;
        __builtin_nontemporal_store(o, (f4nt*)&out[fb4 + k * 64 + lane]);
    }
}

extern "C" void kernel_launch(void* const* d_in, const int* in_sizes, int n_in,
                              void* d_out, int out_size, void* d_ws, size_t ws_size,
                              hipStream_t stream) {
    const float* log_x0 = (const float*)d_in[0];
    const float* u      = (const float*)d_in[1];
    const int*   t_ptr  = (const int*)d_in[2];
    float* out = (float*)d_out;

    const int nfeat = in_sizes[0] / 32;   // B*F = 1,048,576
    const int ntile = nfeat / 64;         // 16384 tiles
    const int nblk  = ntile / 4;          // 4 tile-waves + 1 traj-wave per block

    sample_kernel<<<nblk, 320, 0, stream>>>((const float4*)log_x0,
                                            (const float4*)u,
                                            log_x0, t_ptr,
                                            (float4*)out);
}

// Round 20
// 109.764 us; speedup vs baseline: 7.3107x; 7.3107x over previous
//
#include <hip/hip_runtime.h>
#include <math.h>

// -----------------------------------------------------------------------------
// Round 20 = r17 (best: 126us total) with ONE delta: 1-WAVE BLOCKS (64 thr).
// r19's per-block traj fold serialized every block-generation on the f64
// chain (802us) — reverted. The untested knob across all ~110us structures:
// block coupling. 4-wave blocks = 33KB LDS = 4 blocks/CU = 38-40% occupancy,
// with a block-wide barrier coupling all 4 waves. Here: 1 tile per 1-wave
// block -> barrier intra-wave, 8.3KB LDS -> ~19 blocks/CU (~59% occupancy),
// +50% concurrent memory phases. Body otherwise byte-identical to r17.
// d_ws: [0..31] lh, [32..63] lc, [64] coldv.
// -----------------------------------------------------------------------------

typedef float f4nt __attribute__((ext_vector_type(4)));

__device__ __forceinline__ float cr_logf32(float x) { return (float)log((double)x); }

__device__ __forceinline__ float cr_g(float u) {
    float c0 = __fadd_rn(u, 1e-30f);
    float t2 = cr_logf32(c0);
    float t3 = __fadd_rn(-t2, 1e-30f);
    float t4 = cr_logf32(t3);
    return -t4;
}

__global__ void traj_kernel(const float* __restrict__ log_x0,
                            const int* __restrict__ t_ptr,
                            float* __restrict__ traj) {
    __shared__ float ac[1001];
    __shared__ float sig[1000];
    __shared__ float init2[2];
    int t = *t_ptr;
    if (t > 1000) t = 1000;
    if (t < 0) t = 0;

    for (int s = threadIdx.x; s <= t; s += blockDim.x) {
        float a = __fdiv_rn((float)s, 1000.0f);
        float b = __fadd_rn(a, 0.008f);
        float c = __fdiv_rn(b, 1.008f);
        float d = __fmul_rn(c, 0x1.921fb6p+1f);  // fl32(pi)
        float e = __fmul_rn(d, 0.5f);
        float cs = (float)cos((double)e);        // CR f32 cos
        ac[s] = __fmul_rn(cs, cs);
    }
    if (threadIdx.x == 0) {
        float hotf = -1e30f, coldf = 1e30f;
        for (int j = 0; j < 32; ++j) {
            float v = log_x0[j];
            hotf = fmaxf(hotf, v);
            coldf = fminf(coldf, v);
        }
        init2[0] = hotf;
        init2[1] = coldf;
        traj[64] = coldf;
    }
    __syncthreads();
    for (int s = threadIdx.x + 1; s <= t; s += blockDim.x)
        sig[s - 1] = __fsub_rn(1.0f, __fdiv_rn(ac[s], ac[s - 1]));
    __syncthreads();

    if (threadIdx.x < 32) {
        const int h = threadIdx.x;   // hot-bin position (einsum f32 sum order)
        float lh = init2[0];
        float lc = init2[1];
        for (int k = 0; k < t; ++k) {
            float sg = sig[k];
            float ph = (float)exp((double)lh);
            float pc = (float)exp((double)lc);
            float th = __fmul_rn(ph, 0.03125f);
            float tc = __fmul_rn(pc, 0.03125f);
            float acc = 0.0f;
            for (int i = 0; i < 32; ++i)
                acc = __fadd_rn(acc, (i == h) ? th : tc);
            float s1  = __fsub_rn(1.0f, sg);
            float sm  = __fmul_rn(sg, acc);
            float phn = __fadd_rn(__fmul_rn(s1, ph), sm);
            float pcn = __fadd_rn(__fmul_rn(s1, pc), sm);
            lh = cr_logf32(__fadd_rn(phn, 1e-8f));
            lc = cr_logf32(__fadd_rn(pcn, 1e-8f));
        }
        traj[h]      = lh;
        traj[32 + h] = lc;
    }
}

// branchless scan step: mask hot bin, track top-2 value + first-visited index
#define SCANB(VAL, IDX)                                         \
    {                                                           \
        const float cu = ((IDX) == hc) ? -1.0f : (VAL);         \
        const bool gt1 = cu > t1u;                              \
        const bool gt2 = cu > t2u;                              \
        t2u = gt1 ? t1u : (gt2 ? cu : t2u);                     \
        t1i = gt1 ? (IDX) : t1i;                                \
        t1u = gt1 ? cu : t1u;                                   \
    }

__global__ void __launch_bounds__(64) sample_kernel(
        const float4* __restrict__ log_x0,
        const float4* __restrict__ u,
        const float* __restrict__ trajm,
        float4* __restrict__ out) {
    __shared__ float lds_u[2048];                // 64 feat x 32 f32 (one tile)
    __shared__ unsigned char lds_h[64];          // hot bin per feature
    __shared__ float lh_s[32], lc_s[32];
    __shared__ float coldv_s;
    if (threadIdx.x < 32) {
        lh_s[threadIdx.x] = trajm[threadIdx.x];
        lc_s[threadIdx.x] = trajm[32 + threadIdx.x];
    }
    if (threadIdx.x == 0) coldv_s = trajm[64];

    const int lane = threadIdx.x;                // 0..63 (one wave per block)
    const int tile = blockIdx.x;
    const size_t fb4 = (size_t)tile * 512;       // float4 base of tile

    // ---- issue ALL 16 loads up-front ----
    float4 xr[8];
    #pragma unroll
    for (int k = 0; k < 8; ++k) xr[k] = log_x0[fb4 + k * 64 + lane];
    float4 ur[8];
    #pragma unroll
    for (int k = 0; k < 8; ++k) ur[k] = u[fb4 + k * 64 + lane];

    // ---- x: ballot per 8-lane subgroup -> hot byte per feature ----
    const int sgb = lane & ~7;                   // subgroup base lane
    #pragma unroll
    for (int k = 0; k < 8; ++k) {
        const float4 xv = xr[k];
        int p = -1;
        p = (xv.x > -1.0f) ? 0 : p;
        p = (xv.y > -1.0f) ? 1 : p;
        p = (xv.z > -1.0f) ? 2 : p;
        p = (xv.w > -1.0f) ? 3 : p;
        const unsigned long long bal = __ballot(p >= 0);
        const unsigned mm = (unsigned)((bal >> sgb) & 0xFFull);
        const int hlane = (int)__ffs(mm) - 1;            // 0..7 or -1
        const int psrc  = __shfl(p, sgb + ((hlane < 0) ? 0 : hlane), 64);
        const int hbin  = (hlane < 0) ? 255 : (hlane * 4 + psrc);
        if ((lane & 7) == 0)
            lds_h[k * 8 + (lane >> 3)] = (unsigned char)hbin;
    }

    // ---- u: linear LDS store (global layout == [feature][bin] already) ----
    #pragma unroll
    for (int k = 0; k < 8; ++k)
        *(float4*)&lds_u[k * 256 + lane * 4] = ur[k];

    __syncthreads();                             // intra-wave: near-free

    // ---- per-lane: own one feature; rotated float4 reads ----
    const int   h  = (int)lds_h[lane];
    const int   hc = (h > 31) ? 0 : h;
    const float lh = lh_s[hc];
    const float lc = lc_s[hc];
    const float coldv = coldv_s;
    const float4* urow4 = (const float4*)&lds_u[lane * 32];

    float t1u = -1.0f, t2u = -1.0f; int t1i = 0;
    #pragma unroll
    for (int q = 0; q < 8; ++q) {
        const int qq = (q + lane) & 7;           // bank rotation across lanes
        const float4 v = urow4[qq];
        const int b0 = qq * 4;
        SCANB(v.x, b0) SCANB(v.y, b0 + 1) SCANB(v.z, b0 + 2) SCANB(v.w, b0 + 3)
    }
    const float uhot = lds_u[lane * 32 + hc];

    const float s_hot  = __fadd_rn(lh, cr_g(uhot));
    const float s_cold = __fadd_rn(lc, cr_g(t1u));
    int widx;
    if (s_hot > s_cold)      widx = hc;
    else if (s_hot < s_cold) widx = t1i;
    else                     widx = (hc < t1i) ? hc : t1i;   // exact tie

    // ---- in-wave exact fixup for plateau/defensive features (rare) ----
    const bool flagged = ((t1u - t2u) < 1e-6f) | (h > 31);
    unsigned long long fm = __ballot(flagged);
    while (fm) {                                 // wave-uniform loop
        const int fl = (int)__builtin_ctzll(fm);
        fm &= fm - 1;
        const int fh  = (int)lds_h[fl];
        const int fhc = (fh > 31) ? 0 : fh;
        const int l32 = lane & 31;
        const float uj  = lds_u[fl * 32 + l32];
        const bool jhot = (l32 == fhc) && (fh <= 31);
        float s = __fadd_rn(jhot ? lh_s[fhc] : lc_s[fhc], cr_g(uj));
        int idx = l32;
        #pragma unroll
        for (int m = 16; m > 0; m >>= 1) {
            float os = __shfl_xor(s,   m, 32);
            int   oi = __shfl_xor(idx, m, 32);
            if (os > s || (os == s && oi < idx)) { s = os; idx = oi; }
        }
        if (lane == fl) widx = idx;              // owner lane takes exact result
    }

    // ---- store: coalesced all-cold, winner patched via shfl; NT stores ----
    #pragma unroll
    for (int k = 0; k < 8; ++k) {
        const int src = k * 8 + (lane >> 3);     // owner lane of this float4
        const int wk  = __shfl(widx, src, 64);
        const int qb  = (lane & 7) * 4;          // bins covered: qb..qb+3
        f4nt o;
        o.x = (wk == qb    ) ? 0.0f : coldv;
        o.y = (wk == qb + 1) ? 0.0f : coldv;
        o.z = (wk == qb + 2) ? 0.0f : coldv;
        o.w = (wk == qb + 3) ? 0.0f : coldv;
        __builtin_nontemporal_store(o, (f4nt*)&out[fb4 + k * 64 + lane]);
    }
}

extern "C" void kernel_launch(void* const* d_in, const int* in_sizes, int n_in,
                              void* d_out, int out_size, void* d_ws, size_t ws_size,
                              hipStream_t stream) {
    const float* log_x0 = (const float*)d_in[0];
    const float* u      = (const float*)d_in[1];
    const int*   t_ptr  = (const int*)d_in[2];
    float* out  = (float*)d_out;
    float* traj = (float*)d_ws;

    const int nfeat = in_sizes[0] / 32;   // B*F = 1,048,576
    const int ntile = nfeat / 64;         // 16384 tiles, one per 1-wave block

    traj_kernel<<<1, 128, 0, stream>>>(log_x0, t_ptr, traj);

    sample_kernel<<<ntile, 64, 0, stream>>>((const float4*)log_x0,
                                            (const float4*)u, traj,
                                            (float4*)out);
}